// Round 18
// baseline (896.847 us; speedup 1.0000x reference)
//
#include <hip/hip_runtime.h>

// ---------------------------------------------------------------------------
// MozafariMNIST2018 — R18 INSTRUMENTATION: R17 structure (best, 129.9us) with
// conv1_fill x4, recompute x24, finalize x16 idempotent inner-reps so each
// surfaces in rocprof top-5 with counters. Per-rep = dispatch_dur / reps.
// ---------------------------------------------------------------------------

typedef unsigned short u16;
typedef unsigned char u8;
typedef __attribute__((ext_vector_type(8))) short short8;
typedef __attribute__((ext_vector_type(4))) float f32x4;
typedef __attribute__((ext_vector_type(4))) float float4v;

#define T_STEPS 15

// ws byte offsets (all 16B aligned)
#define INPCL_OFF   0u
#define SPKCL_OFF   6612480u
#define SPKROW_OFF  13067520u
#define W1CL_OFF    19119120u
#define WHI_OFF     19139600u
#define WLO_OFF     19287056u
#define MAXV_OFF    19434512u
#define ARGM_OFF    19818512u
#define WINMAP_OFF  20202512u
#define POTWIN_OFF  20228112u
#define CNT_OFF     20612112u
#define RSTHR_OFF   20813840u
#define RSMETA_OFF  20814864u

#define NB_REPACK 1615
#define NB_W1     40
#define NB_W2     288
#define NB_BORD   76
#define NB_BROW   18
#define NB_MISC   2
#define PREP_GRID (NB_REPACK + NB_W1 + NB_W2 + NB_BORD + NB_BROW + NB_MISC)

#define NB_CONV1  1500
#define NB_FILL   2048
#define K1B_GRID  (NB_CONV1 + NB_FILL)

#define NB_BMFMA  75
#define WS_GRID   (NB_BMFMA + 375)

static __device__ __forceinline__ u16 f2bf_rne(float f) {
  unsigned u = __float_as_uint(f);
  unsigned r = u + 0x7FFFu + ((u >> 16) & 1u);
  return (u16)(r >> 16);
}
static __device__ __forceinline__ float bf2f(u16 b) {
  return __uint_as_float(((unsigned)b) << 16);
}

static __device__ __forceinline__ void ring_decode(int r, int& h, int& w) {
  if (r < 80) { h = 0; w = r; }
  else if (r < 160) { h = 79; w = r - 80; }
  else if (r < 238) { h = 1 + (r - 160); w = 0; }
  else { h = 1 + (r - 238); w = 79; }
}

// ---------------------------------------------------------------------------
// K1: prep — layouts, rowsums, rings (unrepped; bounded < 6us by R15)
__global__ __launch_bounds__(256) void prep_kernel(
    const int* __restrict__ xin, const float* __restrict__ w1,
    const float* __restrict__ w2, u16* __restrict__ inp_cl,
    u16* __restrict__ w1cl, u16* __restrict__ Whi, u16* __restrict__ Wlo,
    u16* __restrict__ spk_cl, u16* __restrict__ spk_row,
    u16* __restrict__ cnt, float* __restrict__ rs_thr,
    float* __restrict__ rsmeta) {
  int tid = threadIdx.x, b = blockIdx.x;

  if (b < NB_REPACK) {
    int g = b * 256 + tid;
    if (g < 413280) {
      int t = g / 27552, rem = g % 27552;
      int yy = rem / 168, xx = rem % 168;
      int y = yy - 2, x = xx - 2;
      short8 sv = {0, 0, 0, 0, 0, 0, 0, 0};
      if ((unsigned)y < 160u && (unsigned)x < 160u) {
        const int* xb = xin + ((size_t)t * 6 * 160 + y) * 160 + x;
#pragma unroll
        for (int c = 0; c < 6; ++c)
          sv[c] = xb[c * 25600] ? (short)0x3F80 : (short)0;
      }
      *(short8*)(inp_cl + (size_t)g * 8) = sv;
    }
  } else if (b < NB_REPACK + NB_W1) {
    int idx = (b - NB_REPACK) * 256 + tid;
    int f = idx / 320, r = idx % 320;
    int ky = r / 64, r2 = r % 64;
    int kxb = r2 >> 5, k = r2 & 31;
    int dx = k >> 3, c = k & 7;
    int kx = kxb * 4 + dx;
    u16 v = 0;
    if (f < 30 && c < 6 && kx < 5)
      v = f2bf_rne(w1[(f * 6 + c) * 25 + ky * 5 + kx]);
    w1cl[idx] = v;
  } else if (b < NB_REPACK + NB_W1 + NB_W2) {
    int g2 = (b - NB_REPACK - NB_W1) * 256 + tid;
    int f = g2 / 288, r = g2 % 288;
    int kk = r >> 5, c = r & 31;
    u16 h = 0, l = 0;
    if (f < 250 && c < 30) {
      float w = w2[f * 270 + c * 9 + kk];
      h = f2bf_rne(w);
      l = f2bf_rne(w - bf2f(h));
    }
    Whi[g2] = h;
    Wlo[g2] = l;
  } else if (b < NB_REPACK + NB_W1 + NB_W2 + NB_BORD) {
    int u = (b - NB_REPACK - NB_W1 - NB_W2) * 256 + tid;
    if (u < 19440) {
      int pid = u >> 2, part = u & 3;
      int t = pid / 324, i = pid % 324;
      int row, col;
      if (i < 82) { row = 0; col = i; }
      else if (i < 164) { row = 81; col = i - 82; }
      else if (i < 244) { row = 1 + (i - 164); col = 0; }
      else { row = 1 + (i - 244); col = 81; }
      short8 z = {0, 0, 0, 0, 0, 0, 0, 0};
      *(short8*)(spk_cl + (((size_t)t * 82 + row) * 82 + col) * 32 +
                 part * 8) = z;
    }
  } else if (b < NB_REPACK + NB_W1 + NB_W2 + NB_BORD + NB_BROW) {
    int u0 = (b - NB_REPACK - NB_W1 - NB_W2 - NB_BORD) * 256 + tid;
    for (int v = u0; v < 145800; v += NB_BROW * 256) {
      int tc = v / 324, i = v % 324;
      int row, col;
      if (i < 82) { row = 0; col = i; }
      else if (i < 164) { row = 81; col = i - 82; }
      else if (i < 244) { row = 1 + (i - 164); col = 0; }
      else { row = 1 + (i - 244); col = 81; }
      spk_row[(size_t)tc * 6724 + row * 82 + col] = 0;
    }
  } else if (b == NB_REPACK + NB_W1 + NB_W2 + NB_BORD + NB_BROW) {
    __shared__ float sv[256];
    __shared__ int si[256];
    float a = 0.f;
    if (tid < 250) {
      const float* wt = w2 + tid * 270;
      for (int c = 0; c < 30; ++c)
#pragma unroll
        for (int kk = 0; kk < 9; ++kk)
          a = fmaf(wt[c * 9 + kk], 1.0f, a);
    }
    float thr = (a >= 10.f) ? a : 0.f;
    if (tid < 250) rs_thr[tid] = thr;
    sv[tid] = (tid < 250) ? thr : -1.f;
    si[tid] = tid;
    __syncthreads();
    for (int s = 128; s > 0; s >>= 1) {
      if (tid < s) {
        if (sv[tid + s] > sv[tid] ||
            (sv[tid + s] == sv[tid] && si[tid + s] < si[tid])) {
          sv[tid] = sv[tid + s];
          si[tid] = si[tid + s];
        }
      }
      __syncthreads();
    }
    if (tid == 0) {
      rsmeta[0] = sv[0];
      ((int*)rsmeta)[1] = si[0];
    }
  } else {
    for (int i = tid; i < 4860; i += 256) {
      int t = i / 324, r = i % 324;
      int row, col;
      if (r < 82) { row = 0; col = r; }
      else if (r < 164) { row = 81; col = r - 82; }
      else if (r < 244) { row = 1 + (r - 164); col = 0; }
      else { row = 1 + (r - 244); col = 81; }
      cnt[t * 6724 + row * 82 + col] = 0;
    }
  }
}

// ---------------------------------------------------------------------------
// K2: conv1 MFMA (LDS tile) + cnt plane || d_out zero fill — x reps
__global__ __launch_bounds__(256) void conv1_fill_kernel(
    const u16* __restrict__ inp_cl, const u16* __restrict__ w1cl,
    u16* __restrict__ spk_cl, u16* __restrict__ spk_row,
    u16* __restrict__ cnt, float4v* __restrict__ out4, int out_n4,
    int reps) {
  __shared__ __align__(16) u16 tile[20 * 24 * 8];
  __shared__ u8 fires[30 * 256];
  __shared__ u16 pooled[64 * 32];

  int tid = threadIdx.x, b = blockIdx.x;

  for (int rep = 0; rep < reps; ++rep) {
    asm volatile("" ::: "memory");
    if (b >= NB_CONV1) {
      int i = (b - NB_CONV1) * 256 + tid;
      float4v z = {0.f, 0.f, 0.f, 0.f};
      for (; i < out_n4; i += NB_FILL * 256) out4[i] = z;
      continue;
    }

    __syncthreads();   // rep boundary: protect LDS reuse

    int t = b / 100, tile_id = b % 100;
    int ty0 = (tile_id / 10) * 16, tx0 = (tile_id % 10) * 16;
    int lane = tid & 63, wave = tid >> 6, lrow = lane & 15, lgrp = lane >> 4;

    const u16* ib = inp_cl + (size_t)t * 164 * 168 * 8;
    for (int i = tid; i < 480; i += 256) {
      int row = i / 24, col = i % 24;
      *(short8*)&tile[i * 8] =
          *(const short8*)(ib + (((ty0 + row) * 168) + tx0 + col) * 8);
    }

    short8 afr[2][10];
#pragma unroll
    for (int mt = 0; mt < 2; ++mt)
#pragma unroll
      for (int s = 0; s < 10; ++s)
        afr[mt][s] = *(const short8*)(w1cl + ((mt * 16 + lrow) * 10 + s) * 32 +
                                      lgrp * 8);

    __syncthreads();

    for (int ph = 0; ph < 4; ++ph) {
      int rrow = ph * 4 + wave;
      f32x4 acc0 = {0.f, 0.f, 0.f, 0.f}, acc1 = {0.f, 0.f, 0.f, 0.f};
#pragma unroll
      for (int s = 0; s < 10; ++s) {
        int ky = s >> 1, kxb = s & 1;
        short8 bfr = *(const short8*)&tile[
            ((rrow + ky) * 24 + lrow + kxb * 4 + lgrp) * 8];
        acc0 = __builtin_amdgcn_mfma_f32_16x16x32_bf16(afr[0][s], bfr, acc0,
                                                       0, 0, 0);
        acc1 = __builtin_amdgcn_mfma_f32_16x16x32_bf16(afr[1][s], bfr, acc1,
                                                       0, 0, 0);
      }
#pragma unroll
      for (int r = 0; r < 4; ++r) {
        int f0 = lgrp * 4 + r;
        fires[f0 * 256 + rrow * 16 + lrow] = (acc0[r] >= 15.f);
        int f1 = 16 + lgrp * 4 + r;
        if (f1 < 30) fires[f1 * 256 + rrow * 16 + lrow] = (acc1[r] >= 15.f);
      }
    }
    __syncthreads();

    int pby0 = (ty0 >> 1) + 1, pbx0 = (tx0 >> 1) + 1;

    for (int idx = tid; idx < 2048; idx += 256) {
      int f = idx >> 6, pp = idx & 63;
      int py = pp >> 3, px = pp & 7;
      u16 v = 0;
      if (f < 30) {
        const u8* fb = &fires[f * 256 + py * 32 + px * 2];
        v = (fb[0] | fb[1] | fb[16] | fb[17]) ? (u16)0x3F80 : (u16)0;
      }
      pooled[pp * 32 + f] = v;
    }
    for (int idx = tid; idx < 1920; idx += 256) {
      int f = idx >> 6, pp = idx & 63;
      int py = pp >> 3, px = pp & 7;
      const u8* fb = &fires[f * 256 + py * 32 + px * 2];
      u16 v = (fb[0] | fb[1] | fb[16] | fb[17]) ? (u16)0x3F80 : (u16)0;
      spk_row[((t * 30 + f) * 82 + pby0 + py) * 82 + pbx0 + px] = v;
    }
    __syncthreads();

    int pos = tid >> 2, part = tid & 3;
    int yy = pby0 + (pos >> 3), xx = pbx0 + (pos & 7);
    *(short8*)(spk_cl + (((size_t)t * 82 + yy) * 82 + xx) * 32 + part * 8) =
        *(short8*)&pooled[pos * 32 + part * 8];

    if (tid < 64) {
      int c = 0;
#pragma unroll
      for (int f = 0; f < 30; ++f) c += (pooled[tid * 32 + f] != 0) ? 1 : 0;
      cnt[t * 6724 + (pby0 + (tid >> 3)) * 82 + (pbx0 + (tid & 7))] = (u16)c;
    }
  }
}

// ---------------------------------------------------------------------------
// K3: winsparse — border MFMA || interior classify (unrepped; < 12us by R15)
__global__ __launch_bounds__(256) void winsparse_kernel(
    const u16* __restrict__ spk_cl, const u16* __restrict__ spk_row,
    const u16* __restrict__ cnt, const u16* __restrict__ Whi,
    const u16* __restrict__ Wlo, const float* __restrict__ w2,
    const float* __restrict__ rsmeta, float* __restrict__ maxv_ws,
    int* __restrict__ argm_ws) {
  int tid = threadIdx.x, b = blockIdx.x;

  if (b >= NB_BMFMA) {
    int g = (b - NB_BMFMA) * 256 + tid;
    int t = g / 6400, pos = g % 6400;
    int h = pos / 80, w = pos % 80;
    if (h == 0 || h == 79 || w == 0 || w == 79) return;
    const u16* cb = cnt + t * 6724;
    int W = 0;
#pragma unroll
    for (int ky = 0; ky < 3; ++ky) {
      const u16* r = cb + (h + ky) * 82 + w;
      W += r[0] + r[1] + r[2];
    }
    if (W == 270) {
      maxv_ws[g] = rsmeta[0];
      argm_ws[g] = ((const int*)rsmeta)[1];
    } else {
      const u16* srb = spk_row + (size_t)t * 30 * 6724;
      float bv = -1.f; int bf = 0;
      for (int f = 0; f < 250; ++f) {
        const float* wt = w2 + f * 270;
        float a = 0.f;
        for (int c = 0; c < 30; ++c)
#pragma unroll
          for (int ky = 0; ky < 3; ++ky)
#pragma unroll
            for (int kx = 0; kx < 3; ++kx)
              a = fmaf(wt[c * 9 + ky * 3 + kx],
                       bf2f(srb[c * 6724 + (h + ky) * 82 + (w + kx)]), a);
        float v = (a >= 10.f) ? a : 0.f;
        if (v > bv) { bv = v; bf = f; }
      }
      maxv_ws[g] = bv;
      argm_ws[g] = bf;
    }
    return;
  }

  __shared__ __align__(16) u16 Xt[64 * 320];
  __shared__ int eid[64];

  if (tid < 64) {
    int e = b * 64 + tid;
    if (e >= 4740) e = 4739;
    int t = e / 316, r = e % 316;
    int h, w;
    ring_decode(r, h, w);
    eid[tid] = t * 6400 + h * 80 + w;
  }
  __syncthreads();

  for (int task = tid; task < 2304; task += 256) {
    int e = task / 36, r = task % 36;
    int kk = r >> 2, part = r & 3;
    int g = eid[e];
    int t = g / 6400, pos = g % 6400;
    int h = pos / 80, w = pos % 80;
    int ky = kk / 3, kx = kk % 3;
    short8 v = *(const short8*)(
        spk_cl + (((size_t)t * 82 + h + ky) * 82 + (w + kx)) * 32 + part * 8);
    int off = (e * 320 + kk * 32 + part * 8) ^ ((e & 7) << 3);
    *(short8*)(Xt + off) = v;
  }
  __syncthreads();

  int lane = tid & 63, wave = tid >> 6, lrow = lane & 15, lgrp = lane >> 4;
  int fbase = wave * 64;

  f32x4 acc[4][4];
#pragma unroll
  for (int i = 0; i < 4; ++i)
#pragma unroll
    for (int j = 0; j < 4; ++j) acc[i][j] = (f32x4){0.f, 0.f, 0.f, 0.f};

  const u16* whib = Whi + (fbase + lrow) * 288 + lgrp * 8;
  const u16* wlob = Wlo + (fbase + lrow) * 288 + lgrp * 8;
  int xorr = (lrow & 7) << 3;

#pragma unroll
  for (int ks = 0; ks < 9; ++ks) {
    short8 ahi[4], alo[4], bfr[4];
#pragma unroll
    for (int ft = 0; ft < 4; ++ft) {
      ahi[ft] = *(const short8*)(whib + ft * 16 * 288 + ks * 32);
      alo[ft] = *(const short8*)(wlob + ft * 16 * 288 + ks * 32);
    }
#pragma unroll
    for (int pt = 0; pt < 4; ++pt) {
      int s = ((pt * 16 + lrow) * 320 + ks * 32 + lgrp * 8) ^ xorr;
      bfr[pt] = *(const short8*)(Xt + s);
    }
#pragma unroll
    for (int ft = 0; ft < 4; ++ft)
#pragma unroll
      for (int pt = 0; pt < 4; ++pt) {
        acc[ft][pt] = __builtin_amdgcn_mfma_f32_16x16x32_bf16(
            ahi[ft], bfr[pt], acc[ft][pt], 0, 0, 0);
        acc[ft][pt] = __builtin_amdgcn_mfma_f32_16x16x32_bf16(
            alo[ft], bfr[pt], acc[ft][pt], 0, 0, 0);
      }
  }

  __syncthreads();
  float* redv = (float*)Xt;
  int* redi = (int*)(Xt + 512);

#pragma unroll
  for (int pt = 0; pt < 4; ++pt) {
    float bv = -1.f; int bf = 0;
#pragma unroll
    for (int ft = 0; ft < 4; ++ft)
#pragma unroll
      for (int r = 0; r < 4; ++r) {
        float v = acc[ft][pt][r];
        v = (v >= 10.f) ? v : 0.f;
        int f = fbase + ft * 16 + lgrp * 4 + r;
        if (v > bv) { bv = v; bf = f; }
      }
    {
      float ov = __shfl_xor(bv, 16); int of = __shfl_xor(bf, 16);
      if (ov > bv || (ov == bv && of < bf)) { bv = ov; bf = of; }
      ov = __shfl_xor(bv, 32); of = __shfl_xor(bf, 32);
      if (ov > bv || (ov == bv && of < bf)) { bv = ov; bf = of; }
    }
    if (lgrp == 0) {
      redv[wave * 64 + pt * 16 + lrow] = bv;
      redi[wave * 64 + pt * 16 + lrow] = bf;
    }
  }
  __syncthreads();
  if (tid < 64) {
    float bv = -1.f; int bf = 0x7fffffff;
#pragma unroll
    for (int w = 0; w < 4; ++w) {
      float v = redv[w * 64 + tid]; int f = redi[w * 64 + tid];
      if (v > bv || (v == bv && f < bf)) { bv = v; bf = f; }
    }
    int g = eid[tid];
    maxv_ws[g] = bv;
    argm_ws[g] = bf;
  }
}

// ---------------------------------------------------------------------------
// K4: winmap + recompute + fused scatter — x reps
__global__ __launch_bounds__(256) void recompute_kernel(
    const u16* __restrict__ spk_row, const float* __restrict__ w2,
    const u16* __restrict__ cnt, const float* __restrict__ rs_thr,
    const float* __restrict__ maxv, const int* __restrict__ argm,
    int* __restrict__ winmap, float* __restrict__ potwin,
    float* __restrict__ out, int reps) {
  __shared__ u16 patch[30 * 18 * 18];
  __shared__ int anyp;

  int tid = threadIdx.x, b = blockIdx.x;
  int t = b / 25, tile = b % 25;
  int ty0 = (tile / 5) * 16, tx0 = (tile % 5) * 16;
  int py = tid >> 4, px = tid & 15;
  int h = ty0 + py, w = tx0 + px;
  int pos = h * 80 + w;

  for (int rep = 0; rep < reps; ++rep) {
    asm volatile("" ::: "memory");
    __syncthreads();   // rep boundary: protect LDS reuse

    const u16* cb = cnt + t * 6724;
    int W = 0;
#pragma unroll
    for (int ky = 0; ky < 3; ++ky) {
      const u16* r = cb + (h + ky) * 82 + w;
      W += r[0] + r[1] + r[2];
    }
    int partial = (W != 270);
    if (tid == 0) anyp = 0;
    __syncthreads();
    if (partial) anyp = 1;
    __syncthreads();
    int do_stage = anyp;

    if (do_stage) {
      const u16* base = spk_row + (size_t)t * 30 * 6724;
      unsigned* p32 = (unsigned*)patch;
      for (int idx = tid; idx < 4860; idx += 256) {
        int c = idx / 162, rem = idx % 162;
        int dy = rem / 9, dxp = rem % 9;
        p32[idx] = *(const unsigned*)(base + c * 6724 + (ty0 + dy) * 82 +
                                      tx0 + dxp * 2);
      }
    }

    int nc = 0;
#pragma unroll
    for (int tt = 0; tt < T_STEPS; ++tt)
      nc += (maxv[tt * 6400 + pos] > 0.f) ? 1 : 0;
    int e = T_STEPS - nc; if (e > 14) e = 14;
    int win = argm[e * 6400 + pos];
    if (!(maxv[14 * 6400 + pos] > 0.f)) win = -1;
    if (t == 0) winmap[pos] = win;

    if (do_stage) __syncthreads();

    float p = 0.f;
    if (win >= 0) {
      if (!partial) {
        p = rs_thr[win];
      } else {
        const float* wt = w2 + win * 270;
        float a = 0.f;
        for (int c = 0; c < 30; ++c) {
#pragma unroll
          for (int ky = 0; ky < 3; ++ky)
#pragma unroll
            for (int kx = 0; kx < 3; ++kx)
              a = fmaf(wt[c * 9 + ky * 3 + kx],
                       bf2f(patch[c * 324 + (py + ky) * 18 + (px + kx)]), a);
        }
        p = (a >= 10.f) ? a : 0.f;
      }
    }
    potwin[t * 6400 + pos] = p;

    if (win >= 0) {
      int o = (t * 250 + win) * 6400 + pos;
      out[o] = (p > 0.f) ? 1.f : 0.f;
      out[24000000 + o] = p;
    }
  }
}

// ---------------------------------------------------------------------------
// K5: get_k_winners — single block, x reps
__global__ __launch_bounds__(1024) void finalize_kernel(
    const int* __restrict__ winmap, const float* __restrict__ potwin,
    float* __restrict__ out_win, int reps) {
  __shared__ float tv[6400];
  __shared__ int   tf[6400];
  __shared__ float wv_s[16];
  __shared__ int   wk_s[16];
  __shared__ int   sh_w[4];
  __shared__ float vmax_s;

  int tid = threadIdx.x;
  int lane = tid & 63, wid = tid >> 6;

  for (int rep = 0; rep < reps; ++rep) {
    asm volatile("" ::: "memory");
    __syncthreads();   // rep boundary

    float localmax = 0.f;
    for (int pos = tid; pos < 6400; pos += 1024) {
      int win = winmap[pos];
      float val = 0.f; int nspk = 0;
      if (win >= 0) {
#pragma unroll
        for (int t = 0; t < T_STEPS; ++t)
          nspk += (potwin[t * 6400 + pos] > 0.f) ? 1 : 0;
        int first = T_STEPS - nspk; if (first > 14) first = 14;
        val = potwin[first * 6400 + pos];
        if (nspk > 0 && val > localmax) localmax = val;
      }
      tv[pos] = val;
      tf[pos] = ((win + 1) << 4) | nspk;
    }
#pragma unroll
    for (int m = 1; m < 64; m <<= 1)
      localmax = fmaxf(localmax, __shfl_xor(localmax, m));
    if (lane == 0) wv_s[wid] = localmax;
    __syncthreads();
    if (tid == 0) {
      float m = 0.f;
#pragma unroll
      for (int w = 0; w < 16; ++w) m = fmaxf(m, wv_s[w]);
      vmax_s = m * (float)T_STEPS;
    }
    __syncthreads();
    float v = vmax_s;

    for (int pos = tid; pos < 6400; pos += 1024) {
      int meta = tf[pos];
      int win = (meta >> 4) - 1, nspk = meta & 15;
      tf[pos] = win;
      tv[pos] = (win >= 0) ? (float)nspk * (tv[pos] + v) : 0.f;
    }
    __syncthreads();

    for (int it = 0; it < 8; ++it) {
      float bv = -1.f; int bk = 0x7fffffff;
      for (int pos = tid; pos < 6400; pos += 1024) {
        float tvv = tv[pos];
        int key = tf[pos] * 6400 + pos;
        if (tvv > bv || (tvv == bv && key < bk)) { bv = tvv; bk = key; }
      }
#pragma unroll
      for (int m = 1; m < 64; m <<= 1) {
        float ov = __shfl_xor(bv, m); int ok = __shfl_xor(bk, m);
        if (ov > bv || (ov == bv && ok < bk)) { bv = ov; bk = ok; }
      }
      if (lane == 0) { wv_s[wid] = bv; wk_s[wid] = bk; }
      __syncthreads();
      if (tid == 0) {
        float mbv = -1.f; int mbk = 0x7fffffff;
#pragma unroll
        for (int w = 0; w < 16; ++w) {
          float ov = wv_s[w]; int ok = wk_s[w];
          if (ov > mbv || (ov == mbv && ok < mbk)) { mbv = ov; mbk = ok; }
        }
        int f = -1, r = -1, c = -1, valid = 0;
        if (mbv != 0.f) {
          f = mbk / 6400; int pos = mbk % 6400;
          r = pos / 80; c = pos % 80;
          valid = 1;
        }
        out_win[it * 3 + 0] = (float)f;
        out_win[it * 3 + 1] = (float)r;
        out_win[it * 3 + 2] = (float)c;
        sh_w[0] = f; sh_w[1] = r; sh_w[2] = c; sh_w[3] = valid;
      }
      __syncthreads();
      if (sh_w[3]) {
        int wf = sh_w[0], wr = sh_w[1], wc = sh_w[2];
        for (int pos = tid; pos < 6400; pos += 1024) {
          int r = pos / 80, c = pos % 80;
          int dr = r - wr; if (dr < 0) dr = -dr;
          int dc = c - wc; if (dc < 0) dc = -dc;
          if (tf[pos] == wf || (dr <= 1 && dc <= 1)) tv[pos] = 0.f;
        }
      }
      __syncthreads();
    }
  }
}

// ---------------------------------------------------------------------------
extern "C" void kernel_launch(void* const* d_in, const int* in_sizes, int n_in,
                              void* d_out, int out_size, void* d_ws,
                              size_t ws_size, hipStream_t stream) {
  const int*   xin = (const int*)d_in[0];
  const float* w1  = (const float*)d_in[1];
  const float* w2  = (const float*)d_in[2];
  float* out = (float*)d_out;
  char*  ws  = (char*)d_ws;

  u16*   inp_cl  = (u16*)(ws + INPCL_OFF);
  u16*   spk_cl  = (u16*)(ws + SPKCL_OFF);
  u16*   spk_row = (u16*)(ws + SPKROW_OFF);
  u16*   w1cl    = (u16*)(ws + W1CL_OFF);
  u16*   Whi     = (u16*)(ws + WHI_OFF);
  u16*   Wlo     = (u16*)(ws + WLO_OFF);
  float* maxv    = (float*)(ws + MAXV_OFF);
  int*   argm    = (int*)(ws + ARGM_OFF);
  int*   winmap  = (int*)(ws + WINMAP_OFF);
  float* potwin  = (float*)(ws + POTWIN_OFF);
  u16*   cnt     = (u16*)(ws + CNT_OFF);
  float* rs_thr  = (float*)(ws + RSTHR_OFF);
  float* rsmeta  = (float*)(ws + RSMETA_OFF);

  prep_kernel<<<PREP_GRID, 256, 0, stream>>>(xin, w1, w2, inp_cl, w1cl, Whi,
                                             Wlo, spk_cl, spk_row, cnt,
                                             rs_thr, rsmeta);
  conv1_fill_kernel<<<K1B_GRID, 256, 0, stream>>>(inp_cl, w1cl, spk_cl,
                                                  spk_row, cnt,
                                                  (float4v*)d_out,
                                                  out_size / 4, 4);
  winsparse_kernel<<<WS_GRID, 256, 0, stream>>>(spk_cl, spk_row, cnt, Whi,
                                                Wlo, w2, rsmeta, maxv, argm);
  recompute_kernel<<<375, 256, 0, stream>>>(spk_row, w2, cnt, rs_thr, maxv,
                                            argm, winmap, potwin, out, 24);
  finalize_kernel<<<1, 1024, 0, stream>>>(winmap, potwin, out + 48000000,
                                          16);
}

// Round 19
// 127.197 us; speedup vs baseline: 7.0508x; 7.0508x over previous
//
#include <hip/hip_runtime.h>

// ---------------------------------------------------------------------------
// MozafariMNIST2018 SNN forward (training branch, max_layer==2) for MI355X.
//
//  R19: finalize's phase-1 (96K cross-XCD potwin reads from ONE block =
//  31.4us, R18 instrumentation) split into a 25-block prefin kernel;
//  finalize keeps only the 6400-entry suppression rounds (~4us).
//  Everything else identical to R17 (best verified, absmax 0).
//   K1 : prep | K2 : conv1-MFMA (LDS tile) + cnt || d_out fill
//   K3 : winsparse | K4 : winmap + recompute + fused scatter
//   K5 : prefin (per-pos val/nspk/meta + per-block max, 25 blocks)
//   K6 : get_k_winners (single block, LDS-resident)
// ---------------------------------------------------------------------------

typedef unsigned short u16;
typedef unsigned char u8;
typedef __attribute__((ext_vector_type(8))) short short8;
typedef __attribute__((ext_vector_type(4))) float f32x4;
typedef __attribute__((ext_vector_type(4))) float float4v;

#define T_STEPS 15

// ws byte offsets (all 16B aligned)
#define INPCL_OFF   0u
#define SPKCL_OFF   6612480u
#define SPKROW_OFF  13067520u
#define W1CL_OFF    19119120u
#define WHI_OFF     19139600u
#define WLO_OFF     19287056u
#define MAXV_OFF    19434512u
#define ARGM_OFF    19818512u
#define WINMAP_OFF  20202512u
#define POTWIN_OFF  20228112u
#define CNT_OFF     20612112u
#define RSTHR_OFF   20813840u
#define RSMETA_OFF  20814864u
#define VALG_OFF    20814880u   // 6400 f32
#define META_OFF    20840480u   // 6400 i32
#define PMAX_OFF    20866080u   // 32 f32

#define NB_REPACK 1615
#define NB_W1     40
#define NB_W2     288
#define NB_BORD   76
#define NB_BROW   18
#define NB_MISC   2
#define PREP_GRID (NB_REPACK + NB_W1 + NB_W2 + NB_BORD + NB_BROW + NB_MISC)

#define NB_CONV1  1500
#define NB_FILL   2048
#define K1B_GRID  (NB_CONV1 + NB_FILL)

#define NB_BMFMA  75
#define WS_GRID   (NB_BMFMA + 375)

static __device__ __forceinline__ u16 f2bf_rne(float f) {
  unsigned u = __float_as_uint(f);
  unsigned r = u + 0x7FFFu + ((u >> 16) & 1u);
  return (u16)(r >> 16);
}
static __device__ __forceinline__ float bf2f(u16 b) {
  return __uint_as_float(((unsigned)b) << 16);
}

static __device__ __forceinline__ void ring_decode(int r, int& h, int& w) {
  if (r < 80) { h = 0; w = r; }
  else if (r < 160) { h = 79; w = r - 80; }
  else if (r < 238) { h = 1 + (r - 160); w = 0; }
  else { h = 1 + (r - 238); w = 79; }
}

// ---------------------------------------------------------------------------
// K1: prep — layouts, rowsums, rings
__global__ __launch_bounds__(256) void prep_kernel(
    const int* __restrict__ xin, const float* __restrict__ w1,
    const float* __restrict__ w2, u16* __restrict__ inp_cl,
    u16* __restrict__ w1cl, u16* __restrict__ Whi, u16* __restrict__ Wlo,
    u16* __restrict__ spk_cl, u16* __restrict__ spk_row,
    u16* __restrict__ cnt, float* __restrict__ rs_thr,
    float* __restrict__ rsmeta) {
  int tid = threadIdx.x, b = blockIdx.x;

  if (b < NB_REPACK) {
    int g = b * 256 + tid;
    if (g < 413280) {
      int t = g / 27552, rem = g % 27552;
      int yy = rem / 168, xx = rem % 168;
      int y = yy - 2, x = xx - 2;
      short8 sv = {0, 0, 0, 0, 0, 0, 0, 0};
      if ((unsigned)y < 160u && (unsigned)x < 160u) {
        const int* xb = xin + ((size_t)t * 6 * 160 + y) * 160 + x;
#pragma unroll
        for (int c = 0; c < 6; ++c)
          sv[c] = xb[c * 25600] ? (short)0x3F80 : (short)0;
      }
      *(short8*)(inp_cl + (size_t)g * 8) = sv;
    }
  } else if (b < NB_REPACK + NB_W1) {
    int idx = (b - NB_REPACK) * 256 + tid;
    int f = idx / 320, r = idx % 320;
    int ky = r / 64, r2 = r % 64;
    int kxb = r2 >> 5, k = r2 & 31;
    int dx = k >> 3, c = k & 7;
    int kx = kxb * 4 + dx;
    u16 v = 0;
    if (f < 30 && c < 6 && kx < 5)
      v = f2bf_rne(w1[(f * 6 + c) * 25 + ky * 5 + kx]);
    w1cl[idx] = v;
  } else if (b < NB_REPACK + NB_W1 + NB_W2) {
    int g2 = (b - NB_REPACK - NB_W1) * 256 + tid;
    int f = g2 / 288, r = g2 % 288;
    int kk = r >> 5, c = r & 31;
    u16 h = 0, l = 0;
    if (f < 250 && c < 30) {
      float w = w2[f * 270 + c * 9 + kk];
      h = f2bf_rne(w);
      l = f2bf_rne(w - bf2f(h));
    }
    Whi[g2] = h;
    Wlo[g2] = l;
  } else if (b < NB_REPACK + NB_W1 + NB_W2 + NB_BORD) {
    int u = (b - NB_REPACK - NB_W1 - NB_W2) * 256 + tid;
    if (u < 19440) {
      int pid = u >> 2, part = u & 3;
      int t = pid / 324, i = pid % 324;
      int row, col;
      if (i < 82) { row = 0; col = i; }
      else if (i < 164) { row = 81; col = i - 82; }
      else if (i < 244) { row = 1 + (i - 164); col = 0; }
      else { row = 1 + (i - 244); col = 81; }
      short8 z = {0, 0, 0, 0, 0, 0, 0, 0};
      *(short8*)(spk_cl + (((size_t)t * 82 + row) * 82 + col) * 32 +
                 part * 8) = z;
    }
  } else if (b < NB_REPACK + NB_W1 + NB_W2 + NB_BORD + NB_BROW) {
    int u0 = (b - NB_REPACK - NB_W1 - NB_W2 - NB_BORD) * 256 + tid;
    for (int v = u0; v < 145800; v += NB_BROW * 256) {
      int tc = v / 324, i = v % 324;
      int row, col;
      if (i < 82) { row = 0; col = i; }
      else if (i < 164) { row = 81; col = i - 82; }
      else if (i < 244) { row = 1 + (i - 164); col = 0; }
      else { row = 1 + (i - 244); col = 81; }
      spk_row[(size_t)tc * 6724 + row * 82 + col] = 0;
    }
  } else if (b == NB_REPACK + NB_W1 + NB_W2 + NB_BORD + NB_BROW) {
    __shared__ float sv[256];
    __shared__ int si[256];
    float a = 0.f;
    if (tid < 250) {
      const float* wt = w2 + tid * 270;
      for (int c = 0; c < 30; ++c)
#pragma unroll
        for (int kk = 0; kk < 9; ++kk)
          a = fmaf(wt[c * 9 + kk], 1.0f, a);
    }
    float thr = (a >= 10.f) ? a : 0.f;
    if (tid < 250) rs_thr[tid] = thr;
    sv[tid] = (tid < 250) ? thr : -1.f;
    si[tid] = tid;
    __syncthreads();
    for (int s = 128; s > 0; s >>= 1) {
      if (tid < s) {
        if (sv[tid + s] > sv[tid] ||
            (sv[tid + s] == sv[tid] && si[tid + s] < si[tid])) {
          sv[tid] = sv[tid + s];
          si[tid] = si[tid + s];
        }
      }
      __syncthreads();
    }
    if (tid == 0) {
      rsmeta[0] = sv[0];
      ((int*)rsmeta)[1] = si[0];
    }
  } else {
    for (int i = tid; i < 4860; i += 256) {
      int t = i / 324, r = i % 324;
      int row, col;
      if (r < 82) { row = 0; col = r; }
      else if (r < 164) { row = 81; col = r - 82; }
      else if (r < 244) { row = 1 + (r - 164); col = 0; }
      else { row = 1 + (r - 244); col = 81; }
      cnt[t * 6724 + row * 82 + col] = 0;
    }
  }
}

// ---------------------------------------------------------------------------
// K2: conv1 MFMA with LDS-staged input tile (+cnt plane) || d_out zero fill.
__global__ __launch_bounds__(256) void conv1_fill_kernel(
    const u16* __restrict__ inp_cl, const u16* __restrict__ w1cl,
    u16* __restrict__ spk_cl, u16* __restrict__ spk_row,
    u16* __restrict__ cnt, float4v* __restrict__ out4, int out_n4) {
  __shared__ __align__(16) u16 tile[20 * 24 * 8];
  __shared__ u8 fires[30 * 256];
  __shared__ u16 pooled[64 * 32];

  int tid = threadIdx.x, b = blockIdx.x;

  if (b >= NB_CONV1) {
    int i = (b - NB_CONV1) * 256 + tid;
    float4v z = {0.f, 0.f, 0.f, 0.f};
    for (; i < out_n4; i += NB_FILL * 256) out4[i] = z;
    return;
  }

  int t = b / 100, tile_id = b % 100;
  int ty0 = (tile_id / 10) * 16, tx0 = (tile_id % 10) * 16;
  int lane = tid & 63, wave = tid >> 6, lrow = lane & 15, lgrp = lane >> 4;

  const u16* ib = inp_cl + (size_t)t * 164 * 168 * 8;
  for (int i = tid; i < 480; i += 256) {
    int row = i / 24, col = i % 24;
    *(short8*)&tile[i * 8] =
        *(const short8*)(ib + (((ty0 + row) * 168) + tx0 + col) * 8);
  }

  short8 afr[2][10];
#pragma unroll
  for (int mt = 0; mt < 2; ++mt)
#pragma unroll
    for (int s = 0; s < 10; ++s)
      afr[mt][s] =
          *(const short8*)(w1cl + ((mt * 16 + lrow) * 10 + s) * 32 + lgrp * 8);

  __syncthreads();

  for (int ph = 0; ph < 4; ++ph) {
    int rrow = ph * 4 + wave;
    f32x4 acc0 = {0.f, 0.f, 0.f, 0.f}, acc1 = {0.f, 0.f, 0.f, 0.f};
#pragma unroll
    for (int s = 0; s < 10; ++s) {
      int ky = s >> 1, kxb = s & 1;
      short8 bfr = *(const short8*)&tile[
          ((rrow + ky) * 24 + lrow + kxb * 4 + lgrp) * 8];
      acc0 = __builtin_amdgcn_mfma_f32_16x16x32_bf16(afr[0][s], bfr, acc0,
                                                     0, 0, 0);
      acc1 = __builtin_amdgcn_mfma_f32_16x16x32_bf16(afr[1][s], bfr, acc1,
                                                     0, 0, 0);
    }
#pragma unroll
    for (int r = 0; r < 4; ++r) {
      int f0 = lgrp * 4 + r;
      fires[f0 * 256 + rrow * 16 + lrow] = (acc0[r] >= 15.f);
      int f1 = 16 + lgrp * 4 + r;
      if (f1 < 30) fires[f1 * 256 + rrow * 16 + lrow] = (acc1[r] >= 15.f);
    }
  }
  __syncthreads();

  int pby0 = (ty0 >> 1) + 1, pbx0 = (tx0 >> 1) + 1;

  for (int idx = tid; idx < 2048; idx += 256) {
    int f = idx >> 6, pp = idx & 63;
    int py = pp >> 3, px = pp & 7;
    u16 v = 0;
    if (f < 30) {
      const u8* fb = &fires[f * 256 + py * 32 + px * 2];
      v = (fb[0] | fb[1] | fb[16] | fb[17]) ? (u16)0x3F80 : (u16)0;
    }
    pooled[pp * 32 + f] = v;
  }
  for (int idx = tid; idx < 1920; idx += 256) {
    int f = idx >> 6, pp = idx & 63;
    int py = pp >> 3, px = pp & 7;
    const u8* fb = &fires[f * 256 + py * 32 + px * 2];
    u16 v = (fb[0] | fb[1] | fb[16] | fb[17]) ? (u16)0x3F80 : (u16)0;
    spk_row[((t * 30 + f) * 82 + pby0 + py) * 82 + pbx0 + px] = v;
  }
  __syncthreads();

  int pos = tid >> 2, part = tid & 3;
  int yy = pby0 + (pos >> 3), xx = pbx0 + (pos & 7);
  *(short8*)(spk_cl + (((size_t)t * 82 + yy) * 82 + xx) * 32 + part * 8) =
      *(short8*)&pooled[pos * 32 + part * 8];

  if (tid < 64) {
    int c = 0;
#pragma unroll
    for (int f = 0; f < 30; ++f) c += (pooled[tid * 32 + f] != 0) ? 1 : 0;
    cnt[t * 6724 + (pby0 + (tid >> 3)) * 82 + (pbx0 + (tid & 7))] = (u16)c;
  }
}

// ---------------------------------------------------------------------------
// K3: winsparse — border MFMA (blocks 0..74) || interior classify (75..449)
__global__ __launch_bounds__(256) void winsparse_kernel(
    const u16* __restrict__ spk_cl, const u16* __restrict__ spk_row,
    const u16* __restrict__ cnt, const u16* __restrict__ Whi,
    const u16* __restrict__ Wlo, const float* __restrict__ w2,
    const float* __restrict__ rsmeta, float* __restrict__ maxv_ws,
    int* __restrict__ argm_ws) {
  int tid = threadIdx.x, b = blockIdx.x;

  if (b >= NB_BMFMA) {
    int g = (b - NB_BMFMA) * 256 + tid;
    int t = g / 6400, pos = g % 6400;
    int h = pos / 80, w = pos % 80;
    if (h == 0 || h == 79 || w == 0 || w == 79) return;
    const u16* cb = cnt + t * 6724;
    int W = 0;
#pragma unroll
    for (int ky = 0; ky < 3; ++ky) {
      const u16* r = cb + (h + ky) * 82 + w;
      W += r[0] + r[1] + r[2];
    }
    if (W == 270) {
      maxv_ws[g] = rsmeta[0];
      argm_ws[g] = ((const int*)rsmeta)[1];
    } else {
      const u16* srb = spk_row + (size_t)t * 30 * 6724;
      float bv = -1.f; int bf = 0;
      for (int f = 0; f < 250; ++f) {
        const float* wt = w2 + f * 270;
        float a = 0.f;
        for (int c = 0; c < 30; ++c)
#pragma unroll
          for (int ky = 0; ky < 3; ++ky)
#pragma unroll
            for (int kx = 0; kx < 3; ++kx)
              a = fmaf(wt[c * 9 + ky * 3 + kx],
                       bf2f(srb[c * 6724 + (h + ky) * 82 + (w + kx)]), a);
        float v = (a >= 10.f) ? a : 0.f;
        if (v > bv) { bv = v; bf = f; }
      }
      maxv_ws[g] = bv;
      argm_ws[g] = bf;
    }
    return;
  }

  __shared__ __align__(16) u16 Xt[64 * 320];
  __shared__ int eid[64];

  if (tid < 64) {
    int e = b * 64 + tid;
    if (e >= 4740) e = 4739;
    int t = e / 316, r = e % 316;
    int h, w;
    ring_decode(r, h, w);
    eid[tid] = t * 6400 + h * 80 + w;
  }
  __syncthreads();

  for (int task = tid; task < 2304; task += 256) {
    int e = task / 36, r = task % 36;
    int kk = r >> 2, part = r & 3;
    int g = eid[e];
    int t = g / 6400, pos = g % 6400;
    int h = pos / 80, w = pos % 80;
    int ky = kk / 3, kx = kk % 3;
    short8 v = *(const short8*)(
        spk_cl + (((size_t)t * 82 + h + ky) * 82 + (w + kx)) * 32 + part * 8);
    int off = (e * 320 + kk * 32 + part * 8) ^ ((e & 7) << 3);
    *(short8*)(Xt + off) = v;
  }
  __syncthreads();

  int lane = tid & 63, wave = tid >> 6, lrow = lane & 15, lgrp = lane >> 4;
  int fbase = wave * 64;

  f32x4 acc[4][4];
#pragma unroll
  for (int i = 0; i < 4; ++i)
#pragma unroll
    for (int j = 0; j < 4; ++j) acc[i][j] = (f32x4){0.f, 0.f, 0.f, 0.f};

  const u16* whib = Whi + (fbase + lrow) * 288 + lgrp * 8;
  const u16* wlob = Wlo + (fbase + lrow) * 288 + lgrp * 8;
  int xorr = (lrow & 7) << 3;

#pragma unroll
  for (int ks = 0; ks < 9; ++ks) {
    short8 ahi[4], alo[4], bfr[4];
#pragma unroll
    for (int ft = 0; ft < 4; ++ft) {
      ahi[ft] = *(const short8*)(whib + ft * 16 * 288 + ks * 32);
      alo[ft] = *(const short8*)(wlob + ft * 16 * 288 + ks * 32);
    }
#pragma unroll
    for (int pt = 0; pt < 4; ++pt) {
      int s = ((pt * 16 + lrow) * 320 + ks * 32 + lgrp * 8) ^ xorr;
      bfr[pt] = *(const short8*)(Xt + s);
    }
#pragma unroll
    for (int ft = 0; ft < 4; ++ft)
#pragma unroll
      for (int pt = 0; pt < 4; ++pt) {
        acc[ft][pt] = __builtin_amdgcn_mfma_f32_16x16x32_bf16(
            ahi[ft], bfr[pt], acc[ft][pt], 0, 0, 0);
        acc[ft][pt] = __builtin_amdgcn_mfma_f32_16x16x32_bf16(
            alo[ft], bfr[pt], acc[ft][pt], 0, 0, 0);
      }
  }

  __syncthreads();
  float* redv = (float*)Xt;
  int* redi = (int*)(Xt + 512);

#pragma unroll
  for (int pt = 0; pt < 4; ++pt) {
    float bv = -1.f; int bf = 0;
#pragma unroll
    for (int ft = 0; ft < 4; ++ft)
#pragma unroll
      for (int r = 0; r < 4; ++r) {
        float v = acc[ft][pt][r];
        v = (v >= 10.f) ? v : 0.f;
        int f = fbase + ft * 16 + lgrp * 4 + r;
        if (v > bv) { bv = v; bf = f; }
      }
    {
      float ov = __shfl_xor(bv, 16); int of = __shfl_xor(bf, 16);
      if (ov > bv || (ov == bv && of < bf)) { bv = ov; bf = of; }
      ov = __shfl_xor(bv, 32); of = __shfl_xor(bf, 32);
      if (ov > bv || (ov == bv && of < bf)) { bv = ov; bf = of; }
    }
    if (lgrp == 0) {
      redv[wave * 64 + pt * 16 + lrow] = bv;
      redi[wave * 64 + pt * 16 + lrow] = bf;
    }
  }
  __syncthreads();
  if (tid < 64) {
    float bv = -1.f; int bf = 0x7fffffff;
#pragma unroll
    for (int w = 0; w < 4; ++w) {
      float v = redv[w * 64 + tid]; int f = redi[w * 64 + tid];
      if (v > bv || (v == bv && f < bf)) { bv = v; bf = f; }
    }
    int g = eid[tid];
    maxv_ws[g] = bv;
    argm_ws[g] = bf;
  }
}

// ---------------------------------------------------------------------------
// K4: winmap + recompute (rowsum fast path) + fused sparse scatter to d_out.
__global__ __launch_bounds__(256) void recompute_kernel(
    const u16* __restrict__ spk_row, const float* __restrict__ w2,
    const u16* __restrict__ cnt, const float* __restrict__ rs_thr,
    const float* __restrict__ maxv, const int* __restrict__ argm,
    int* __restrict__ winmap, float* __restrict__ potwin,
    float* __restrict__ out) {
  __shared__ u16 patch[30 * 18 * 18];
  __shared__ int anyp;

  int tid = threadIdx.x, b = blockIdx.x;
  int t = b / 25, tile = b % 25;
  int ty0 = (tile / 5) * 16, tx0 = (tile % 5) * 16;
  int py = tid >> 4, px = tid & 15;
  int h = ty0 + py, w = tx0 + px;
  int pos = h * 80 + w;

  const u16* cb = cnt + t * 6724;
  int W = 0;
#pragma unroll
  for (int ky = 0; ky < 3; ++ky) {
    const u16* r = cb + (h + ky) * 82 + w;
    W += r[0] + r[1] + r[2];
  }
  int partial = (W != 270);
  if (tid == 0) anyp = 0;
  __syncthreads();
  if (partial) anyp = 1;
  __syncthreads();
  int do_stage = anyp;

  if (do_stage) {
    const u16* base = spk_row + (size_t)t * 30 * 6724;
    unsigned* p32 = (unsigned*)patch;
    for (int idx = tid; idx < 4860; idx += 256) {
      int c = idx / 162, rem = idx % 162;
      int dy = rem / 9, dxp = rem % 9;
      p32[idx] = *(const unsigned*)(base + c * 6724 + (ty0 + dy) * 82 + tx0 +
                                    dxp * 2);
    }
  }

  int nc = 0;
#pragma unroll
  for (int tt = 0; tt < T_STEPS; ++tt)
    nc += (maxv[tt * 6400 + pos] > 0.f) ? 1 : 0;
  int e = T_STEPS - nc; if (e > 14) e = 14;
  int win = argm[e * 6400 + pos];
  if (!(maxv[14 * 6400 + pos] > 0.f)) win = -1;
  if (t == 0) winmap[pos] = win;

  if (do_stage) __syncthreads();

  float p = 0.f;
  if (win >= 0) {
    if (!partial) {
      p = rs_thr[win];
    } else {
      const float* wt = w2 + win * 270;
      float a = 0.f;
      for (int c = 0; c < 30; ++c) {
#pragma unroll
        for (int ky = 0; ky < 3; ++ky)
#pragma unroll
          for (int kx = 0; kx < 3; ++kx)
            a = fmaf(wt[c * 9 + ky * 3 + kx],
                     bf2f(patch[c * 324 + (py + ky) * 18 + (px + kx)]), a);
      }
      p = (a >= 10.f) ? a : 0.f;
    }
  }
  potwin[t * 6400 + pos] = p;

  if (win >= 0) {
    int o = (t * 250 + win) * 6400 + pos;
    out[o] = (p > 0.f) ? 1.f : 0.f;
    out[24000000 + o] = p;
  }
}

// ---------------------------------------------------------------------------
// K5: prefin — per-pos val/nspk/meta + per-block trunc-max (25 blocks)
__global__ __launch_bounds__(256) void prefin_kernel(
    const int* __restrict__ winmap, const float* __restrict__ potwin,
    float* __restrict__ valg, int* __restrict__ meta,
    float* __restrict__ pmax) {
  __shared__ float red[256];

  int tid = threadIdx.x, b = blockIdx.x;
  int pos = b * 256 + tid;

  int win = winmap[pos];
  float val = 0.f; int nspk = 0;
  if (win >= 0) {
#pragma unroll
    for (int t = 0; t < T_STEPS; ++t)
      nspk += (potwin[t * 6400 + pos] > 0.f) ? 1 : 0;
    int first = T_STEPS - nspk; if (first > 14) first = 14;
    val = potwin[first * 6400 + pos];
  }
  valg[pos] = val;
  meta[pos] = ((win + 1) << 4) | nspk;

  red[tid] = (win >= 0 && nspk > 0) ? val : 0.f;
  __syncthreads();
  for (int s = 128; s > 0; s >>= 1) {
    if (tid < s) red[tid] = fmaxf(red[tid], red[tid + s]);
    __syncthreads();
  }
  if (tid == 0) pmax[b] = red[0];
}

// ---------------------------------------------------------------------------
// K6: get_k_winners — single block, all inputs small/L2-resident
__global__ __launch_bounds__(1024) void finalize_kernel(
    const float* __restrict__ valg, const int* __restrict__ meta,
    const float* __restrict__ pmax, float* __restrict__ out_win) {
  __shared__ float tv[6400];
  __shared__ int   tf[6400];
  __shared__ float wv_s[16];
  __shared__ int   wk_s[16];
  __shared__ int   sh_w[4];
  __shared__ float vmax_s;

  int tid = threadIdx.x;
  int lane = tid & 63, wid = tid >> 6;

  if (tid == 0) {
    float m = 0.f;
#pragma unroll
    for (int i = 0; i < 25; ++i) m = fmaxf(m, pmax[i]);
    vmax_s = m * (float)T_STEPS;
  }
  __syncthreads();
  float v = vmax_s;

  for (int pos = tid; pos < 6400; pos += 1024) {
    int me = meta[pos];
    int win = (me >> 4) - 1, nspk = me & 15;
    tf[pos] = win;
    tv[pos] = (win >= 0) ? (float)nspk * (valg[pos] + v) : 0.f;
  }
  __syncthreads();

  for (int it = 0; it < 8; ++it) {
    float bv = -1.f; int bk = 0x7fffffff;
    for (int pos = tid; pos < 6400; pos += 1024) {
      float tvv = tv[pos];
      int key = tf[pos] * 6400 + pos;
      if (tvv > bv || (tvv == bv && key < bk)) { bv = tvv; bk = key; }
    }
#pragma unroll
    for (int m = 1; m < 64; m <<= 1) {
      float ov = __shfl_xor(bv, m); int ok = __shfl_xor(bk, m);
      if (ov > bv || (ov == bv && ok < bk)) { bv = ov; bk = ok; }
    }
    if (lane == 0) { wv_s[wid] = bv; wk_s[wid] = bk; }
    __syncthreads();
    if (tid == 0) {
      float mbv = -1.f; int mbk = 0x7fffffff;
#pragma unroll
      for (int w = 0; w < 16; ++w) {
        float ov = wv_s[w]; int ok = wk_s[w];
        if (ov > mbv || (ov == mbv && ok < mbk)) { mbv = ov; mbk = ok; }
      }
      int f = -1, r = -1, c = -1, valid = 0;
      if (mbv != 0.f) {
        f = mbk / 6400; int pos = mbk % 6400;
        r = pos / 80; c = pos % 80;
        valid = 1;
      }
      out_win[it * 3 + 0] = (float)f;
      out_win[it * 3 + 1] = (float)r;
      out_win[it * 3 + 2] = (float)c;
      sh_w[0] = f; sh_w[1] = r; sh_w[2] = c; sh_w[3] = valid;
    }
    __syncthreads();
    if (sh_w[3]) {
      int wf = sh_w[0], wr = sh_w[1], wc = sh_w[2];
      for (int pos = tid; pos < 6400; pos += 1024) {
        int r = pos / 80, c = pos % 80;
        int dr = r - wr; if (dr < 0) dr = -dr;
        int dc = c - wc; if (dc < 0) dc = -dc;
        if (tf[pos] == wf || (dr <= 1 && dc <= 1)) tv[pos] = 0.f;
      }
    }
    __syncthreads();
  }
}

// ---------------------------------------------------------------------------
extern "C" void kernel_launch(void* const* d_in, const int* in_sizes, int n_in,
                              void* d_out, int out_size, void* d_ws,
                              size_t ws_size, hipStream_t stream) {
  const int*   xin = (const int*)d_in[0];
  const float* w1  = (const float*)d_in[1];
  const float* w2  = (const float*)d_in[2];
  float* out = (float*)d_out;
  char*  ws  = (char*)d_ws;

  u16*   inp_cl  = (u16*)(ws + INPCL_OFF);
  u16*   spk_cl  = (u16*)(ws + SPKCL_OFF);
  u16*   spk_row = (u16*)(ws + SPKROW_OFF);
  u16*   w1cl    = (u16*)(ws + W1CL_OFF);
  u16*   Whi     = (u16*)(ws + WHI_OFF);
  u16*   Wlo     = (u16*)(ws + WLO_OFF);
  float* maxv    = (float*)(ws + MAXV_OFF);
  int*   argm    = (int*)(ws + ARGM_OFF);
  int*   winmap  = (int*)(ws + WINMAP_OFF);
  float* potwin  = (float*)(ws + POTWIN_OFF);
  u16*   cnt     = (u16*)(ws + CNT_OFF);
  float* rs_thr  = (float*)(ws + RSTHR_OFF);
  float* rsmeta  = (float*)(ws + RSMETA_OFF);
  float* valg    = (float*)(ws + VALG_OFF);
  int*   meta    = (int*)(ws + META_OFF);
  float* pmax    = (float*)(ws + PMAX_OFF);

  prep_kernel<<<PREP_GRID, 256, 0, stream>>>(xin, w1, w2, inp_cl, w1cl, Whi,
                                             Wlo, spk_cl, spk_row, cnt,
                                             rs_thr, rsmeta);
  conv1_fill_kernel<<<K1B_GRID, 256, 0, stream>>>(inp_cl, w1cl, spk_cl,
                                                  spk_row, cnt,
                                                  (float4v*)d_out,
                                                  out_size / 4);
  winsparse_kernel<<<WS_GRID, 256, 0, stream>>>(spk_cl, spk_row, cnt, Whi,
                                                Wlo, w2, rsmeta, maxv, argm);
  recompute_kernel<<<375, 256, 0, stream>>>(spk_row, w2, cnt, rs_thr, maxv,
                                            argm, winmap, potwin, out);
  prefin_kernel<<<25, 256, 0, stream>>>(winmap, potwin, valg, meta, pmax);
  finalize_kernel<<<1, 1024, 0, stream>>>(valg, meta, pmax, out + 48000000);
}